// Round 9
// baseline (7696.185 us; speedup 1.0000x reference)
//
#include <hip/hip_runtime.h>
#include <hip/hip_bf16.h>
#include <stdint.h>

// ContainedLSTM: B=128, S=1024, I=256, H=256.
// xw = x@W_ih^T: split-bf16 (Ootomo) MFMA GEMM -> fp32-grade, chunked in ws.
// Recurrence: 16 blocks = 4 group-pairs x 4 j-quarters; each block advances
// TWO independent batch-groups (gp, gp+4) TIME-INTERLEAVED: stream B's
// compute fills stream A's publish->visible latency and vice versa (R4-R8:
// ~3us/step of the 4.4us step is serial exchange latency; compute ~1.2us).
// W_hh*gamma parked in AGPRs (f16, 128 regs, shared by both streams).
// Exchange: R7's tagged u64 via __hip_atomic intrinsics (R8's hand-rolled
// sc0/sc1 wide ops doubled HBM writes -- reverted).

#define Bb 128
#define Ss 1024
#define Ii 256
#define Hh 256
#define G4v 1024
#define EPSF 1e-5f

typedef __bf16 bf16;
typedef _Float16 f16;
typedef __attribute__((ext_vector_type(8))) __bf16 bf16x8;
typedef __attribute__((ext_vector_type(4))) __bf16 bf16x4;
typedef __attribute__((ext_vector_type(8))) _Float16 f16x8;
typedef __attribute__((ext_vector_type(4))) _Float16 f16x4;
typedef __attribute__((ext_vector_type(4))) float f32x4;
typedef unsigned int u32;
typedef unsigned long long u64;

static __device__ __forceinline__ f32x4 mfma16b(bf16x8 a, bf16x8 b, f32x4 c) {
  return __builtin_amdgcn_mfma_f32_16x16x32_bf16(a, b, c, 0, 0, 0);
}
static __device__ __forceinline__ f32x4 mfma16h(f16x8 a, f16x8 b, f32x4 c) {
  return __builtin_amdgcn_mfma_f32_16x16x32_f16(a, b, c, 0, 0, 0);
}
static __device__ __forceinline__ float sigm(float x) { return 1.0f / (1.0f + __expf(-x)); }
static __device__ __forceinline__ float tanhf_(float x) {
  float e = __expf(-2.0f * fabsf(x));
  float t = (1.0f - e) / (1.0f + e);
  return x < 0.0f ? -t : t;
}
static __device__ __forceinline__ unsigned short ush(f16 h) {
  return __builtin_bit_cast(unsigned short, h);
}
static __device__ __forceinline__ f16 hus(unsigned short u) {
  return __builtin_bit_cast(f16, u);
}

// ---------------- prep kernels ----------------
__global__ void k_conv_wih(const float* __restrict__ W, bf16* __restrict__ hi,
                           bf16* __restrict__ lo) {
  int i = (blockIdx.x * 256 + threadIdx.x) * 4;
  f32x4 v = *(const f32x4*)(W + i);
  bf16x4 h_, l_;
#pragma unroll
  for (int j = 0; j < 4; ++j) {
    bf16 hh = (bf16)v[j];
    h_[j] = hh;
    l_[j] = (bf16)(v[j] - (float)hh);
  }
  *(bf16x4*)(hi + i) = h_;
  *(bf16x4*)(lo + i) = l_;
}

// Wtil = W_hh * gamma -> single f16 plane, fragment-linear:
// Wf[(ntg*8+kt)*64 + lane][8] = Wtil[g=ntg*16+(lane&15)][k=kt*32+(lane>>4)*8+j]
__global__ void k_prep_whh(const float* __restrict__ W, const float* __restrict__ gamma,
                           f16* __restrict__ Wf) {
  int tid = blockIdx.x * 256 + threadIdx.x;  // 0..32767
  int lane = tid & 63;
  int fk = tid >> 6;
  int ntg = fk >> 3, kt = fk & 7;
  int g = ntg * 16 + (lane & 15);
  int k = kt * 32 + ((lane >> 4) << 3);
  f16x8 r;
#pragma unroll
  for (int j = 0; j < 8; ++j) r[j] = (f16)(W[g * Hh + k + j] * gamma[k + j]);
  *(f16x8*)(Wf + (size_t)tid * 8) = r;
}

__global__ void k_prep_rd(const float* __restrict__ W, const float* __restrict__ gamma,
                          const float* __restrict__ beta, const float* __restrict__ bih,
                          const float* __restrict__ bhh, float* __restrict__ RD) {
  int g = blockIdx.x * 256 + threadIdx.x;  // 1024 total
  float r = 0.f, d = 0.f;
  for (int k = 0; k < Hh; ++k) {
    float w = W[g * Hh + k];
    r += w * gamma[k];
    d += w * beta[k];
  }
  RD[2 * g] = r;
  RD[2 * g + 1] = d + bih[g] + bhh[g];
}

// ---------------- xw GEMM (split-bf16, unchanged) ----------------
__global__ __launch_bounds__(256, 2) void k_gemm(const float* __restrict__ x,
                                                 const bf16* __restrict__ Whi,
                                                 const bf16* __restrict__ Wlo,
                                                 float* __restrict__ xw,
                                                 int t0, int Tc, int ntb) {
  __shared__ bf16 Bs[2][128 * 128];
  int bid = blockIdx.x;
  int b = bid & 127;
  int r2 = bid >> 7;
  int tb = r2 % ntb;
  int gt = r2 / ntb;
  int g0 = gt * 128;
  int tid = threadIdx.x, w = tid >> 6, lane = tid & 63;
  int li = lane & 15, lg = lane >> 4;
  char* BsB = (char*)Bs;
  int tbase = tb * 128 + 32 * w;
  f32x4 acc[2][8];
#pragma unroll
  for (int mt = 0; mt < 2; ++mt)
#pragma unroll
    for (int nt = 0; nt < 8; ++nt) acc[mt][nt] = (f32x4){0.f, 0.f, 0.f, 0.f};

  for (int kp = 0; kp < 2; ++kp) {
#pragma unroll
    for (int it = 0; it < 8; ++it) {
      int p = it * 4096 + tid * 16;
      int row = p >> 8, colb = p & 255;
      size_t goff = (size_t)(g0 + row) * 512 + kp * 256 + colb;
      int dst = row * 256 + (colb ^ ((row & 7) << 4));
      *(bf16x8*)(BsB + dst) = *(const bf16x8*)((const char*)Whi + goff);
      *(bf16x8*)(BsB + 32768 + dst) = *(const bf16x8*)((const char*)Wlo + goff);
    }
    __syncthreads();
#pragma unroll
    for (int kt = 0; kt < 4; ++kt) {
      int kl = kt * 32 + lg * 8;
      int kgl = kp * 128 + kl;
      bf16x8 ah[2], al[2];
#pragma unroll
      for (int mt = 0; mt < 2; ++mt) {
        int t = t0 + tbase + 16 * mt + li;
        const float* xp = x + ((size_t)b * Ss + t) * Ii + kgl;
        f32x4 f0 = *(const f32x4*)xp;
        f32x4 f1 = *(const f32x4*)(xp + 4);
        bf16x8 hv, lv;
#pragma unroll
        for (int j = 0; j < 4; ++j) {
          bf16 h0 = (bf16)f0[j];
          hv[j] = h0;
          lv[j] = (bf16)(f0[j] - (float)h0);
          bf16 h1 = (bf16)f1[j];
          hv[4 + j] = h1;
          lv[4 + j] = (bf16)(f1[j] - (float)h1);
        }
        ah[mt] = hv;
        al[mt] = lv;
      }
#pragma unroll
      for (int nt = 0; nt < 8; ++nt) {
        int grow = nt * 16 + li;
        int off = grow * 256 + ((kl * 2) ^ ((grow & 7) << 4));
        bf16x8 bh = *(const bf16x8*)(BsB + off);
        bf16x8 bl = *(const bf16x8*)(BsB + 32768 + off);
#pragma unroll
        for (int mt = 0; mt < 2; ++mt) {
          acc[mt][nt] = mfma16b(ah[mt], bh, acc[mt][nt]);
          acc[mt][nt] = mfma16b(ah[mt], bl, acc[mt][nt]);
          acc[mt][nt] = mfma16b(al[mt], bh, acc[mt][nt]);
        }
      }
    }
    __syncthreads();
  }
#pragma unroll
  for (int mt = 0; mt < 2; ++mt)
#pragma unroll
    for (int nt = 0; nt < 8; ++nt)
#pragma unroll
      for (int r = 0; r < 4; ++r) {
        int tl = tbase + 16 * mt + lg * 4 + r;
        int g = g0 + nt * 16 + li;
        xw[((size_t)b * Tc + tl) * G4v + g] = acc[mt][nt][r];
      }
}

// ---------------- recurrence (time-interleaved dual stream) ----------------
// grid: 16 blocks, bid = q*4 + gp; block 256 thr / 4 waves.
__global__ __launch_bounds__(256, 1) void k_recur(
    const f16* __restrict__ Wf, const float* __restrict__ xw,
    const int* __restrict__ mask, const float* __restrict__ RD,
    float* __restrict__ st_h, float* __restrict__ st_c, float* __restrict__ st_o,
    u64* pub, float* __restrict__ out, int t0, int Tc, int first, int last) {
  __shared__ f16 hbA[2][16 * 256];   // stream A h hi/lo planes (swizzled)
  __shared__ f16 hbB[2][16 * 256];   // stream B
  __shared__ float mursA[16][2], mursB[16][2];
  __shared__ float2 spwA[4][16], spwB[4][16];
  __shared__ float spart[16][16][2];  // init-path only
  int bid = blockIdx.x;
  int gp = bid & 3, q = bid >> 2;
  int tid = threadIdx.x, w = tid >> 6, lane = tid & 63;
  int li = lane & 15, lg = lane >> 4;
  int b0A = gp * 16, b0B = (gp + 4) * 16;
  int jloc = (q * 4 + w) * 16 + li;
  char* hbAB = (char*)hbA;
  char* hbBB = (char*)hbB;

  // park this wave's W-quarter (single f16 plane, 128 regs) in AGPRs
  f16x8 wp[4][8];
#pragma unroll
  for (int c = 0; c < 4; ++c)
#pragma unroll
    for (int kt = 0; kt < 8; ++kt) {
      int ntg = c * 16 + q * 4 + w;
      wp[c][kt] = *(const f16x8*)(Wf + ((size_t)(ntg * 8 + kt) * 64 + lane) * 8);
      asm volatile("" : "+a"(wp[c][kt]));
    }
  float Rr[4], Dd[4];
#pragma unroll
  for (int c = 0; c < 4; ++c) {
    int g = c * 256 + jloc;
    Rr[c] = RD[2 * g];
    Dd[c] = RD[2 * g + 1];
  }

  float cstA[4], ostA[4], cstB[4], ostB[4];
  if (first) {
#pragma unroll
    for (int i = 0; i < 16; ++i) {
      hbA[0][tid * 16 + i] = (f16)0.0f;
      hbA[1][tid * 16 + i] = (f16)0.0f;
      hbB[0][tid * 16 + i] = (f16)0.0f;
      hbB[1][tid * 16 + i] = (f16)0.0f;
    }
#pragma unroll
    for (int r = 0; r < 4; ++r) { cstA[r] = 0.f; ostA[r] = 0.f; cstB[r] = 0.f; ostB[r] = 0.f; }
    if (tid < 16) {
      mursA[tid][0] = 0.f; mursA[tid][1] = rsqrtf(EPSF);
      mursB[tid][0] = 0.f; mursB[tid][1] = rsqrtf(EPSF);
    }
  } else {
    int row = tid >> 4, cs = tid & 15, jseg = cs * 16;
    {  // pass A
      float s = 0.f, ss = 0.f;
#pragma unroll
      for (int i = 0; i < 16; ++i) {
        float v = st_h[(size_t)(b0A + row) * Hh + jseg + i];
        s += v; ss += v * v;
        f16 hh = (f16)v;
        int boff = row * 512 + (((jseg + i) * 2) ^ ((row & 7) << 4));
        *(f16*)(hbAB + boff) = hh;
        *(f16*)(hbAB + 8192 + boff) = (f16)(v - (float)hh);
      }
      spart[row][cs][0] = s;
      spart[row][cs][1] = ss;
#pragma unroll
      for (int r = 0; r < 4; ++r) {
        int m = lg * 4 + r;
        cstA[r] = st_c[(size_t)(b0A + m) * Hh + jloc];
        ostA[r] = st_o[(size_t)(b0A + m) * Hh + jloc];
      }
      __syncthreads();
      if (tid < 16) {
        float s2 = 0.f, ss2 = 0.f;
#pragma unroll
        for (int i = 0; i < 16; ++i) { s2 += spart[tid][i][0]; ss2 += spart[tid][i][1]; }
        float mu = s2 * (1.f / 256.f);
        float var = ss2 * (1.f / 256.f) - mu * mu;
        float rs = rsqrtf(var + EPSF);
        mursA[tid][0] = mu * rs;
        mursA[tid][1] = rs;
      }
      __syncthreads();
    }
    {  // pass B
      float s = 0.f, ss = 0.f;
#pragma unroll
      for (int i = 0; i < 16; ++i) {
        float v = st_h[(size_t)(b0B + row) * Hh + jseg + i];
        s += v; ss += v * v;
        f16 hh = (f16)v;
        int boff = row * 512 + (((jseg + i) * 2) ^ ((row & 7) << 4));
        *(f16*)(hbBB + boff) = hh;
        *(f16*)(hbBB + 8192 + boff) = (f16)(v - (float)hh);
      }
      spart[row][cs][0] = s;
      spart[row][cs][1] = ss;
#pragma unroll
      for (int r = 0; r < 4; ++r) {
        int m = lg * 4 + r;
        cstB[r] = st_c[(size_t)(b0B + m) * Hh + jloc];
        ostB[r] = st_o[(size_t)(b0B + m) * Hh + jloc];
      }
      __syncthreads();
      if (tid < 16) {
        float s2 = 0.f, ss2 = 0.f;
#pragma unroll
        for (int i = 0; i < 16; ++i) { s2 += spart[tid][i][0]; ss2 += spart[tid][i][1]; }
        float mu = s2 * (1.f / 256.f);
        float var = ss2 * (1.f / 256.f) - mu * mu;
        float rs = rsqrtf(var + EPSF);
        mursB[tid][0] = mu * rs;
        mursB[tid][1] = rs;
      }
    }
  }
  __syncthreads();

  // preload xw/mask for tl=0 (both streams)
  float xwvA[4][4], xwvB[4][4];
  int mkA[4], mkB[4];
#pragma unroll
  for (int c = 0; c < 4; ++c)
#pragma unroll
    for (int r = 0; r < 4; ++r) {
      xwvA[c][r] = xw[((size_t)(b0A + lg * 4 + r) * Tc + 0) * G4v + c * 256 + jloc];
      xwvB[c][r] = xw[((size_t)(b0B + lg * 4 + r) * Tc + 0) * G4v + c * 256 + jloc];
    }
#pragma unroll
  for (int r = 0; r < 4; ++r) {
    mkA[r] = mask[(size_t)(b0A + lg * 4 + r) * Ss + t0];
    mkB[r] = mask[(size_t)(b0B + lg * 4 + r) * Ss + t0];
  }

  int grow = tid >> 4, gcg = tid & 15;  // gather role: row, col-group

  for (int tl = 0; tl < Tc; ++tl) {
    int tg = t0 + tl;
    int slot = (tg + 1) & 1;
    u32 want = (u32)(tg + 1);

    // ---- [1] MFMA A ----
    f32x4 a0[4], a1[4];
#pragma unroll
    for (int c = 0; c < 4; ++c) {
      a0[c] = (f32x4){0.f, 0.f, 0.f, 0.f};
      a1[c] = (f32x4){0.f, 0.f, 0.f, 0.f};
    }
#pragma unroll
    for (int kt = 0; kt < 8; ++kt) {
      int aoff = li * 512 + (((kt * 32 + lg * 8) * 2) ^ ((li & 7) << 4));
      f16x8 ah = *(const f16x8*)(hbAB + aoff);
      f16x8 al = *(const f16x8*)(hbAB + 8192 + aoff);
#pragma unroll
      for (int c = 0; c < 4; ++c) {
        a0[c] = mfma16h(ah, wp[c][kt], a0[c]);
        a1[c] = mfma16h(al, wp[c][kt], a1[c]);
      }
    }
    float mrsA[4], rsvA[4];
#pragma unroll
    for (int r = 0; r < 4; ++r) {
      int m = lg * 4 + r;
      mrsA[r] = mursA[m][0];
      rsvA[r] = mursA[m][1];
    }
    __syncthreads();  // [2]: all waves done reading hbA + mursA

    // ---- [3] gates A + own hbA slice + publish A + stats A ----
    float hnA[4];
    {
      u64* ph = pub + (size_t)(slot * 32 + bid) * 1024;
#pragma unroll
      for (int r = 0; r < 4; ++r) {
        float i_ = (a0[0][r] + a1[0][r]) * rsvA[r] - mrsA[r] * Rr[0] + Dd[0] + xwvA[0][r];
        float f_ = (a0[1][r] + a1[1][r]) * rsvA[r] - mrsA[r] * Rr[1] + Dd[1] + xwvA[1][r];
        float g_ = (a0[2][r] + a1[2][r]) * rsvA[r] - mrsA[r] * Rr[2] + Dd[2] + xwvA[2][r];
        float o_ = (a0[3][r] + a1[3][r]) * rsvA[r] - mrsA[r] * Rr[3] + Dd[3] + xwvA[3][r];
        float cn = sigm(f_) * cstA[r] + sigm(i_) * tanhf_(g_);
        float hn = sigm(o_) * tanhf_(cn);
        cstA[r] = cn;
        ostA[r] = mkA[r] ? ostA[r] : hn;
        hnA[r] = hn;
        f16 hh = (f16)hn;
        f16 hl = (f16)(hn - (float)hh);
        int m = lg * 4 + r;
        int boff = m * 512 + ((jloc * 2) ^ ((m & 7) << 4));
        *(f16*)(hbAB + boff) = hh;
        *(f16*)(hbAB + 8192 + boff) = hl;
        u64 pv = ((u64)want << 32) | ((u32)ush(hh) << 16) | (u32)ush(hl);
        __hip_atomic_store(&ph[m * 64 + (w * 16 + li)], pv, __ATOMIC_RELAXED,
                           __HIP_MEMORY_SCOPE_AGENT);
      }
      float sr[4], qr[4];
#pragma unroll
      for (int r = 0; r < 4; ++r) { sr[r] = hnA[r]; qr[r] = hnA[r] * hnA[r]; }
#pragma unroll
      for (int msk = 1; msk < 16; msk <<= 1)
#pragma unroll
        for (int r = 0; r < 4; ++r) {
          sr[r] += __shfl_xor(sr[r], msk);
          qr[r] += __shfl_xor(qr[r], msk);
        }
      if (li == 0)
#pragma unroll
        for (int r = 0; r < 4; ++r) spwA[w][lg * 4 + r] = make_float2(sr[r], qr[r]);
    }

    // ---- [4] MFMA B ----
    f32x4 c0[4], c1[4];
#pragma unroll
    for (int c = 0; c < 4; ++c) {
      c0[c] = (f32x4){0.f, 0.f, 0.f, 0.f};
      c1[c] = (f32x4){0.f, 0.f, 0.f, 0.f};
    }
#pragma unroll
    for (int kt = 0; kt < 8; ++kt) {
      int aoff = li * 512 + (((kt * 32 + lg * 8) * 2) ^ ((li & 7) << 4));
      f16x8 ah = *(const f16x8*)(hbBB + aoff);
      f16x8 al = *(const f16x8*)(hbBB + 8192 + aoff);
#pragma unroll
      for (int c = 0; c < 4; ++c) {
        c0[c] = mfma16h(ah, wp[c][kt], c0[c]);
        c1[c] = mfma16h(al, wp[c][kt], c1[c]);
      }
    }
    float mrsB[4], rsvB[4];
#pragma unroll
    for (int r = 0; r < 4; ++r) {
      int m = lg * 4 + r;
      mrsB[r] = mursB[m][0];
      rsvB[r] = mursB[m][1];
    }
    __syncthreads();  // [5]: all waves done reading hbB + mursB

    // ---- [6] gates B + own hbB slice + publish B + stats B ----
    float hnB[4];
    {
      u64* ph = pub + (size_t)(slot * 32 + 16 + bid) * 1024;
#pragma unroll
      for (int r = 0; r < 4; ++r) {
        float i_ = (c0[0][r] + c1[0][r]) * rsvB[r] - mrsB[r] * Rr[0] + Dd[0] + xwvB[0][r];
        float f_ = (c0[1][r] + c1[1][r]) * rsvB[r] - mrsB[r] * Rr[1] + Dd[1] + xwvB[1][r];
        float g_ = (c0[2][r] + c1[2][r]) * rsvB[r] - mrsB[r] * Rr[2] + Dd[2] + xwvB[2][r];
        float o_ = (c0[3][r] + c1[3][r]) * rsvB[r] - mrsB[r] * Rr[3] + Dd[3] + xwvB[3][r];
        float cn = sigm(f_) * cstB[r] + sigm(i_) * tanhf_(g_);
        float hn = sigm(o_) * tanhf_(cn);
        cstB[r] = cn;
        ostB[r] = mkB[r] ? ostB[r] : hn;
        hnB[r] = hn;
        f16 hh = (f16)hn;
        f16 hl = (f16)(hn - (float)hh);
        int m = lg * 4 + r;
        int boff = m * 512 + ((jloc * 2) ^ ((m & 7) << 4));
        *(f16*)(hbBB + boff) = hh;
        *(f16*)(hbBB + 8192 + boff) = hl;
        u64 pv = ((u64)want << 32) | ((u32)ush(hh) << 16) | (u32)ush(hl);
        __hip_atomic_store(&ph[m * 64 + (w * 16 + li)], pv, __ATOMIC_RELAXED,
                           __HIP_MEMORY_SCOPE_AGENT);
      }
      float sr[4], qr[4];
#pragma unroll
      for (int r = 0; r < 4; ++r) { sr[r] = hnB[r]; qr[r] = hnB[r] * hnB[r]; }
#pragma unroll
      for (int msk = 1; msk < 16; msk <<= 1)
#pragma unroll
        for (int r = 0; r < 4; ++r) {
          sr[r] += __shfl_xor(sr[r], msk);
          qr[r] += __shfl_xor(qr[r], msk);
        }
      if (li == 0)
#pragma unroll
        for (int r = 0; r < 4; ++r) spwB[w][lg * 4 + r] = make_float2(sr[r], qr[r]);
    }

    // tail state stores
    if (tl == Tc - 1) {
#pragma unroll
      for (int r = 0; r < 4; ++r) {
        int m = lg * 4 + r;
        st_h[(size_t)(b0A + m) * Hh + jloc] = hnA[r];
        st_c[(size_t)(b0A + m) * Hh + jloc] = cstA[r];
        st_o[(size_t)(b0A + m) * Hh + jloc] = ostA[r];
        st_h[(size_t)(b0B + m) * Hh + jloc] = hnB[r];
        st_c[(size_t)(b0B + m) * Hh + jloc] = cstB[r];
        st_o[(size_t)(b0B + m) * Hh + jloc] = ostB[r];
      }
      if (last) {
#pragma unroll
        for (int r = 0; r < 4; ++r) {
          out[(size_t)(b0A + lg * 4 + r) * Hh + jloc] = ostA[r];
          out[(size_t)(b0B + lg * 4 + r) * Hh + jloc] = ostB[r];
        }
      }
    }

    // ---- [7] prefetch next xw/mask (both) + first gather sweeps ----
    u64 gvA[3][4], gvB[3][4];
    const u64* srcsA[3];
    const u64* srcsB[3];
#pragma unroll
    for (int pi = 0; pi < 3; ++pi) {
      int qq = (q + 1 + pi) & 3;
      int pbid = qq * 4 + gp;
      srcsA[pi] = pub + (size_t)(slot * 32 + pbid) * 1024 + grow * 64 + gcg * 4;
      srcsB[pi] = pub + (size_t)(slot * 32 + 16 + pbid) * 1024 + grow * 64 + gcg * 4;
    }
    {
      int tln = (tl + 1 < Tc) ? tl + 1 : Tc - 1;
#pragma unroll
      for (int c = 0; c < 4; ++c)
#pragma unroll
        for (int r = 0; r < 4; ++r) {
          xwvA[c][r] = xw[((size_t)(b0A + lg * 4 + r) * Tc + tln) * G4v + c * 256 + jloc];
          xwvB[c][r] = xw[((size_t)(b0B + lg * 4 + r) * Tc + tln) * G4v + c * 256 + jloc];
        }
#pragma unroll
      for (int r = 0; r < 4; ++r) {
        mkA[r] = mask[(size_t)(b0A + lg * 4 + r) * Ss + t0 + tln];
        mkB[r] = mask[(size_t)(b0B + lg * 4 + r) * Ss + t0 + tln];
      }
    }
#pragma unroll
    for (int pi = 0; pi < 3; ++pi)
#pragma unroll
      for (int e = 0; e < 4; ++e)
        gvA[pi][e] = __hip_atomic_load(&srcsA[pi][e], __ATOMIC_RELAXED,
                                       __HIP_MEMORY_SCOPE_AGENT);

    // ---- [8] poll A (batch sweep) + unpack -> hbA + remote stats ----
    {
      u32 bad = 0;
#pragma unroll
      for (int pi = 0; pi < 3; ++pi)
#pragma unroll
        for (int e = 0; e < 4; ++e) bad |= (u32)(gvA[pi][e] >> 32) ^ want;
      int cnt = 0;
      while (bad) {
#pragma unroll
        for (int pi = 0; pi < 3; ++pi)
#pragma unroll
          for (int e = 0; e < 4; ++e)
            gvA[pi][e] = __hip_atomic_load(&srcsA[pi][e], __ATOMIC_RELAXED,
                                           __HIP_MEMORY_SCOPE_AGENT);
        bad = 0;
#pragma unroll
        for (int pi = 0; pi < 3; ++pi)
#pragma unroll
          for (int e = 0; e < 4; ++e) bad |= (u32)(gvA[pi][e] >> 32) ^ want;
        if (++cnt > (1 << 20)) break;  // hang insurance
      }
    }
    float suA = 0.f, quA = 0.f;
#pragma unroll
    for (int pi = 0; pi < 3; ++pi) {
      int qq = (q + 1 + pi) & 3;
      int j0 = qq * 64 + gcg * 4;
      int boff = grow * 512 + ((j0 * 2) ^ ((grow & 7) << 4));
      f16x4 h4, l4;
#pragma unroll
      for (int e = 0; e < 4; ++e) {
        u32 d = (u32)gvA[pi][e];
        f16 hh = hus((unsigned short)(d >> 16));
        f16 hl = hus((unsigned short)(d & 0xffffu));
        h4[e] = hh;
        l4[e] = hl;
        float f = (float)hh + (float)hl;
        suA += f;
        quA += f * f;
      }
      *(f16x4*)(hbAB + boff) = h4;
      *(f16x4*)(hbAB + 8192 + boff) = l4;
    }
#pragma unroll
    for (int msk = 1; msk < 16; msk <<= 1) {
      suA += __shfl_xor(suA, msk);
      quA += __shfl_xor(quA, msk);
    }
    // issue stream B's first sweep before the barrier
#pragma unroll
    for (int pi = 0; pi < 3; ++pi)
#pragma unroll
      for (int e = 0; e < 4; ++e)
        gvB[pi][e] = __hip_atomic_load(&srcsB[pi][e], __ATOMIC_RELAXED,
                                       __HIP_MEMORY_SCOPE_AGENT);
    __syncthreads();  // [9]: hbA gathers visible; spwA/spwB visible
    if (li == 0) {
      float s = suA + spwA[0][grow].x + spwA[1][grow].x + spwA[2][grow].x + spwA[3][grow].x;
      float ss2 = quA + spwA[0][grow].y + spwA[1][grow].y + spwA[2][grow].y + spwA[3][grow].y;
      float mu = s * (1.f / 256.f);
      float var = ss2 * (1.f / 256.f) - mu * mu;
      float rs = rsqrtf(var + EPSF);
      mursA[grow][0] = mu * rs;
      mursA[grow][1] = rs;
    }

    // ---- [11] poll B + unpack -> hbB + remote stats ----
    {
      u32 bad = 0;
#pragma unroll
      for (int pi = 0; pi < 3; ++pi)
#pragma unroll
        for (int e = 0; e < 4; ++e) bad |= (u32)(gvB[pi][e] >> 32) ^ want;
      int cnt = 0;
      while (bad) {
#pragma unroll
        for (int pi = 0; pi < 3; ++pi)
#pragma unroll
          for (int e = 0; e < 4; ++e)
            gvB[pi][e] = __hip_atomic_load(&srcsB[pi][e], __ATOMIC_RELAXED,
                                           __HIP_MEMORY_SCOPE_AGENT);
        bad = 0;
#pragma unroll
        for (int pi = 0; pi < 3; ++pi)
#pragma unroll
          for (int e = 0; e < 4; ++e) bad |= (u32)(gvB[pi][e] >> 32) ^ want;
        if (++cnt > (1 << 20)) break;  // hang insurance
      }
    }
    float suB = 0.f, quB = 0.f;
#pragma unroll
    for (int pi = 0; pi < 3; ++pi) {
      int qq = (q + 1 + pi) & 3;
      int j0 = qq * 64 + gcg * 4;
      int boff = grow * 512 + ((j0 * 2) ^ ((grow & 7) << 4));
      f16x4 h4, l4;
#pragma unroll
      for (int e = 0; e < 4; ++e) {
        u32 d = (u32)gvB[pi][e];
        f16 hh = hus((unsigned short)(d >> 16));
        f16 hl = hus((unsigned short)(d & 0xffffu));
        h4[e] = hh;
        l4[e] = hl;
        float f = (float)hh + (float)hl;
        suB += f;
        quB += f * f;
      }
      *(f16x4*)(hbBB + boff) = h4;
      *(f16x4*)(hbBB + 8192 + boff) = l4;
    }
#pragma unroll
    for (int msk = 1; msk < 16; msk <<= 1) {
      suB += __shfl_xor(suB, msk);
      quB += __shfl_xor(quB, msk);
    }
    __syncthreads();  // [12]: hbB gathers + mursA visible
    if (li == 0) {
      float s = suB + spwB[0][grow].x + spwB[1][grow].x + spwB[2][grow].x + spwB[3][grow].x;
      float ss2 = quB + spwB[0][grow].y + spwB[1][grow].y + spwB[2][grow].y + spwB[3][grow].y;
      float mu = s * (1.f / 256.f);
      float var = ss2 * (1.f / 256.f) - mu * mu;
      float rs = rsqrtf(var + EPSF);
      mursB[grow][0] = mu * rs;
      mursB[grow][1] = rs;
    }
    // mursB consumed after next iteration's barrier [2] -> ordered
  }
}

// ---------------- host ----------------
extern "C" void kernel_launch(void* const* d_in, const int* in_sizes, int n_in,
                              void* d_out, int out_size, void* d_ws, size_t ws_size,
                              hipStream_t stream) {
  (void)in_sizes; (void)n_in; (void)out_size;
  const float* x = (const float*)d_in[0];
  const int* mask = (const int*)d_in[1];
  const float* Wih = (const float*)d_in[2];
  const float* Whh = (const float*)d_in[3];
  const float* bih = (const float*)d_in[4];
  const float* bhh = (const float*)d_in[5];
  const float* gamma = (const float*)d_in[6];
  const float* beta = (const float*)d_in[7];
  float* outp = (float*)d_out;
  char* ws = (char*)d_ws;

  const size_t extra = 3 * (512u << 10) + (8u << 10) + 3 * (128u << 10) +
                       (512u << 10) + (64u << 10);
  int Tc = 128;
  if (ws_size >= (size_t)1024 * 524288 + extra) Tc = 1024;
  else if (ws_size >= (size_t)512 * 524288 + extra) Tc = 512;
  else if (ws_size >= (size_t)256 * 524288 + extra) Tc = 256;

  size_t o = 0;
  auto take = [&](size_t bytes) { size_t r = o; o += (bytes + 255) & ~(size_t)255; return r; };
  size_t xw_off = take((size_t)Bb * Tc * G4v * 4);
  size_t wihh_off = take(512u << 10);
  size_t wihl_off = take(512u << 10);
  size_t whh_off = take(512u << 10);
  size_t rd_off = take(8u << 10);
  size_t sth_off = take(128u << 10);
  size_t stc_off = take(128u << 10);
  size_t sto_off = take(128u << 10);
  size_t pub_off = take(512u << 10);

  bf16* wihh = (bf16*)(ws + wihh_off);
  bf16* wihl = (bf16*)(ws + wihl_off);
  f16* whhf = (f16*)(ws + whh_off);
  float* rd = (float*)(ws + rd_off);
  float* xwp = (float*)(ws + xw_off);
  float* sth = (float*)(ws + sth_off);
  float* stc = (float*)(ws + stc_off);
  float* sto = (float*)(ws + sto_off);
  u64* pubh = (u64*)(ws + pub_off);

  // clear pub tags (tag 0 < any step tag) -- removes all staleness hazards
  hipMemsetAsync(pubh, 0, 512u << 10, stream);
  k_conv_wih<<<dim3(256), dim3(256), 0, stream>>>(Wih, wihh, wihl);
  k_prep_whh<<<dim3(128), dim3(256), 0, stream>>>(Whh, gamma, whhf);
  k_prep_rd<<<dim3(4), dim3(256), 0, stream>>>(Whh, gamma, beta, bih, bhh, rd);

  int nchunk = Ss / Tc;
  int ntb = Tc / 128;
  for (int ci = 0; ci < nchunk; ++ci) {
    int t0 = ci * Tc;
    k_gemm<<<dim3(8 * ntb * 128), dim3(256), 0, stream>>>(x, wihh, wihl, xwp, t0, Tc, ntb);
    k_recur<<<dim3(16), dim3(256), 0, stream>>>(whhf, xwp, mask, rd, sth, stc, sto,
                                                pubh, outp, t0, Tc,
                                                ci == 0 ? 1 : 0, ci == nchunk - 1 ? 1 : 0);
  }
}